// Round 2
// baseline (205.012 us; speedup 1.0000x reference)
//
#include <hip/hip_runtime.h>

#define EMB   1024
#define HEADS 16
#define SDIM  64
#define BATCH 2
#define TSEQ  2048
#define BT    (BATCH*TSEQ)   // 4096 rows
#define NBH   (BATCH*HEADS)  // 32

typedef __attribute__((ext_vector_type(8))) short short8;
typedef __attribute__((ext_vector_type(4))) float f32x4;

static __device__ __forceinline__ unsigned short f2bf(float f) {
  unsigned u = __builtin_bit_cast(unsigned, f);
  u = (u + 0x7FFFu + ((u >> 16) & 1u)) >> 16;   // RNE
  return (unsigned short)u;
}

#define MFMA(a, b, c) __builtin_amdgcn_mfma_f32_16x16x32_bf16((a), (b), (c), 0, 0, 0)

#define GLOAD_LDS16(g, l)                                                     \
  __builtin_amdgcn_global_load_lds(                                           \
      (const __attribute__((address_space(1))) unsigned*)(g),                 \
      (__attribute__((address_space(3))) unsigned*)(l), 16, 0, 0)

// ---------------------------------------------------------------- convert
// x (4M f32) -> bf16, and the 3 per-head projection tensors -> bf16.
__global__ __launch_bounds__(256) void convert_kernel(
    const float* __restrict__ x,
    const float* __restrict__ tk, const float* __restrict__ tq,
    const float* __restrict__ tv,
    unsigned short* __restrict__ xb,
    unsigned short* __restrict__ pk, unsigned short* __restrict__ pq,
    unsigned short* __restrict__ pv) {
  const int NX4 = BT * EMB / 4;            // 1048576
  const int NP4 = HEADS * SDIM * SDIM / 4; // 16384
  int i = blockIdx.x * blockDim.x + threadIdx.x;
  const float* src; unsigned short* dst; int off;
  if (i < NX4)               { src = x;  dst = xb; off = i * 4; }
  else if (i < NX4 + NP4)    { src = tk; dst = pk; off = (i - NX4) * 4; }
  else if (i < NX4 + 2*NP4)  { src = tq; dst = pq; off = (i - NX4 - NP4) * 4; }
  else if (i < NX4 + 3*NP4)  { src = tv; dst = pv; off = (i - NX4 - 2*NP4) * 4; }
  else return;
  float4 v = *(const float4*)(src + off);
  ushort4 o;
  o.x = f2bf(v.x); o.y = f2bf(v.y); o.z = f2bf(v.z); o.w = f2bf(v.w);
  *(ushort4*)(dst + off) = o;
}

// ---------------------------------------------------------------- transpose
// W[k][n] f32 -> Wt[n][k] bf16 (both 1024x1024); z selects which matrix.
__global__ __launch_bounds__(256) void transpose_w_kernel(
    const float* __restrict__ w0, const float* __restrict__ w1,
    unsigned short* __restrict__ o0, unsigned short* __restrict__ o1) {
  __shared__ float tile[32][33];
  const float* in        = blockIdx.z ? w1 : w0;
  unsigned short* out    = blockIdx.z ? o1 : o0;
  int r0 = blockIdx.y * 32, c0 = blockIdx.x * 32;
  int tid = threadIdx.x;
  int r = tid >> 3, c4 = (tid & 7) * 4;
  float4 v = *(const float4*)(in + (size_t)(r0 + r) * EMB + c0 + c4);
  tile[r][c4 + 0] = v.x; tile[r][c4 + 1] = v.y;
  tile[r][c4 + 2] = v.z; tile[r][c4 + 3] = v.w;
  __syncthreads();
  ushort4 o;
  o.x = f2bf(tile[c4 + 0][r]);
  o.y = f2bf(tile[c4 + 1][r]);
  o.z = f2bf(tile[c4 + 2][r]);
  o.w = f2bf(tile[c4 + 3][r]);
  *(ushort4*)(out + (size_t)(c0 + r) * EMB + r0 + c4) = o;
}

// ---------------------------------------------------------------- GEMM (NT)
// C[4096][1024] = A[4096][1024] @ Bt[1024][1024]^T, bf16 in, fp32 acc.
// BM=64 BN=128 BK=32, 512 blocks, global_load_lds staging (m97 structure).
// MODE 0: bf16 out, no bias.  MODE 1: fp32 out + bias.
template <int MODE>
__global__ __launch_bounds__(256) void gemm_bt_kernel(
    const unsigned short* __restrict__ A,
    const unsigned short* __restrict__ Bt,
    unsigned short* __restrict__ Cbf, float* __restrict__ Cf,
    const float* __restrict__ bias) {
  __shared__ short As[64 * 32];    // linear, K-fast (required by global_load_lds)
  __shared__ short Bs[128 * 32];
  const int tid = threadIdx.x;
  const int lane = tid & 63;
  const int w = __builtin_amdgcn_readfirstlane(tid >> 6);
  const int wr = w >> 1, wc = w & 1;   // wave covers rows wr*32.., cols wc*64..
  const int l15 = lane & 15, l4 = lane >> 4;
  // XCD-bijective swizzle (nwg = 512, divisible by 8)
  const int flat = blockIdx.y * gridDim.x + blockIdx.x;
  const int vid = (flat & 7) * 64 + (flat >> 3);
  const int m0 = (vid >> 3) * 64;      // 64 m-tiles
  const int n0 = (vid & 7) * 128;      // 8 n-tiles
  const int lrow = lane >> 2, lcol = (lane & 3) * 8;  // staging lane map (16B/lane)
  f32x4 acc[2][4] = {};
  for (int kt = 0; kt < 32; ++kt) {
    const int k0 = kt * 32;
    // 12 chunks of 1KB (A:4, B:8); wave w issues chunks w*3..w*3+2
    for (int i = 0; i < 3; ++i) {
      int c = w * 3 + i;
      if (c < 4) {
        GLOAD_LDS16(A + (size_t)(m0 + c * 16 + lrow) * EMB + k0 + lcol,
                    &As[c * 512]);
      } else {
        int cb = c - 4;
        GLOAD_LDS16(Bt + (size_t)(n0 + cb * 16 + lrow) * EMB + k0 + lcol,
                    &Bs[cb * 512]);
      }
    }
    __syncthreads();   // drains vmcnt -> staged tile visible
    short8 af[2], bf[4];
    for (int mi = 0; mi < 2; ++mi)
      af[mi] = *(short8*)&As[(wr * 32 + mi * 16 + l15) * 32 + l4 * 8];
    for (int ni = 0; ni < 4; ++ni)
      bf[ni] = *(short8*)&Bs[(wc * 64 + ni * 16 + l15) * 32 + l4 * 8];
    __builtin_amdgcn_s_setprio(1);
    for (int mi = 0; mi < 2; ++mi)
      for (int ni = 0; ni < 4; ++ni)
        acc[mi][ni] = MFMA(af[mi], bf[ni], acc[mi][ni]);
    __builtin_amdgcn_s_setprio(0);
    __syncthreads();
  }
  for (int mi = 0; mi < 2; ++mi)
    for (int ni = 0; ni < 4; ++ni) {
      int col = n0 + wc * 64 + ni * 16 + l15;
      for (int r = 0; r < 4; ++r) {
        int row = m0 + wr * 32 + mi * 16 + l4 * 4 + r;
        if (MODE == 0)
          Cbf[(size_t)row * EMB + col] = f2bf(acc[mi][ni][r]);
        else
          Cf[(size_t)row * EMB + col] = acc[mi][ni][r] + bias[col];
      }
    }
}

// ---------------------------------------------------------------- QKV proj
// Per (bh, 64-row t-tile): q/k/v[t][i] = sum_k xd[t][h*64+k] * P[h][i][k].
// Writes Q,K row-major [bh][t][64]; V transposed [bh][64][t].
__global__ __launch_bounds__(256) void proj_qkv_kernel(
    const unsigned short* __restrict__ XD,
    const unsigned short* __restrict__ PK, const unsigned short* __restrict__ PQ,
    const unsigned short* __restrict__ PV,
    unsigned short* __restrict__ Qg, unsigned short* __restrict__ Kg,
    unsigned short* __restrict__ Vt) {
  __shared__ short xs[64 * 72];
  __shared__ short ps[3][64 * 72];
  const int tid = threadIdx.x, lane = tid & 63;
  const int w = __builtin_amdgcn_readfirstlane(tid >> 6);
  const int tt = blockIdx.x, bh = blockIdx.y;
  const int b = bh >> 4, h = bh & 15;
  const int l15 = lane & 15, l4 = lane >> 4;
  const unsigned short* srcs[3] = {PK + h * 4096, PQ + h * 4096, PV + h * 4096};
  for (int u = tid; u < 512; u += 256) {
    int row = u >> 3, ch = (u & 7) * 8;
    *(short8*)&xs[row * 72 + ch] = *(const short8*)(
        XD + (size_t)(b * TSEQ + tt * 64 + row) * EMB + h * 64 + ch);
  }
  for (int m = 0; m < 3; ++m)
    for (int u = tid; u < 512; u += 256) {
      int row = u >> 3, ch = (u & 7) * 8;
      *(short8*)&ps[m][row * 72 + ch] = *(const short8*)(srcs[m] + row * 64 + ch);
    }
  __syncthreads();
  short8 af[2];
  af[0] = *(short8*)&xs[(w * 16 + l15) * 72 + l4 * 8];
  af[1] = *(short8*)&xs[(w * 16 + l15) * 72 + 32 + l4 * 8];
  f32x4 aK[4] = {}, aQ[4] = {}, aV[4] = {};
  for (int ni = 0; ni < 4; ++ni)
    for (int kc = 0; kc < 2; ++kc) {
      short8 bk = *(short8*)&ps[0][(ni * 16 + l15) * 72 + kc * 32 + l4 * 8];
      short8 bq = *(short8*)&ps[1][(ni * 16 + l15) * 72 + kc * 32 + l4 * 8];
      short8 bv = *(short8*)&ps[2][(ni * 16 + l15) * 72 + kc * 32 + l4 * 8];
      aK[ni] = MFMA(af[kc], bk, aK[ni]);
      aQ[ni] = MFMA(af[kc], bq, aQ[ni]);
      aV[ni] = MFMA(af[kc], bv, aV[ni]);
    }
  for (int ni = 0; ni < 4; ++ni)
    for (int r = 0; r < 4; ++r) {
      int t = tt * 64 + w * 16 + l4 * 4 + r;
      size_t o = (size_t)(bh * TSEQ + t) * SDIM + ni * 16 + l15;
      Qg[o] = f2bf(aQ[ni][r]);
      Kg[o] = f2bf(aK[ni][r]);
    }
  __syncthreads();  // everyone done reading xs
  for (int ni = 0; ni < 4; ++ni)
    for (int r = 0; r < 4; ++r)
      xs[(w * 16 + l4 * 4 + r) * 72 + ni * 16 + l15] = (short)f2bf(aV[ni][r]);
  __syncthreads();
  for (int u = tid; u < 512; u += 256) {
    int d = u >> 3, ch = (u & 7) * 8;
    short8 v;
    for (int e = 0; e < 8; ++e) v[e] = xs[(ch + e) * 72 + d];
    *(short8*)(Vt + (size_t)(bh * 64 + d) * TSEQ + tt * 64 + ch) = v;
  }
}

// ---------------------------------------------------------------- attention
// Flash-style, fixed-max softmax (logits provably tiny: |s/8| << 1).
// Double-buffered K/V LDS + register prefetch; 1 barrier/iter.
__global__ __launch_bounds__(256) void attn_kernel(
    const unsigned short* __restrict__ Qg, const unsigned short* __restrict__ Kg,
    const unsigned short* __restrict__ Vt, unsigned short* __restrict__ Og) {
  __shared__ short Ks[2][64 * 64];   // [key][d], XOR-swizzled
  __shared__ short Vs[2][64 * 64];   // [d][key], XOR-swizzled
  __shared__ short Ps[4][16 * 64];   // per-wave P [qrow][key], XOR-swizzled
  const int tid = threadIdx.x, lane = tid & 63;
  const int w = __builtin_amdgcn_readfirstlane(tid >> 6);
  // XCD-bijective swizzle (nwg = 1024): each XCD gets 4 consecutive bh
  const int flat = blockIdx.y * gridDim.x + blockIdx.x;
  const int vid = (flat & 7) * 128 + (flat >> 3);
  const int qt = vid & 31, bh = vid >> 5;
  const int b = bh >> 4, h = bh & 15;
  const int l15 = lane & 15, l4 = lane >> 4;
  short8 qf[2];
  {
    int row = qt * 64 + w * 16 + l15;
    const unsigned short* qp = Qg + (size_t)(bh * TSEQ + row) * SDIM;
    qf[0] = *(const short8*)(qp + l4 * 8);
    qf[1] = *(const short8*)(qp + 32 + l4 * 8);
  }
  const unsigned short* Kbase = Kg + (size_t)bh * TSEQ * SDIM;
  const unsigned short* Vbase = Vt + (size_t)bh * SDIM * TSEQ;
  const int ur = tid >> 3, uc = (tid & 7);   // 32 rows x 8 chunks per half
  float lsum[4] = {0.f, 0.f, 0.f, 0.f};
  f32x4 O[4] = {};
  short8 rk0, rk1, rv0, rv1;
  auto loadKV = [&](int kt) {
    rk0 = *(const short8*)(Kbase + (size_t)(kt * 64 + ur) * SDIM + uc * 8);
    rk1 = *(const short8*)(Kbase + (size_t)(kt * 64 + ur + 32) * SDIM + uc * 8);
    rv0 = *(const short8*)(Vbase + (size_t)ur * TSEQ + kt * 64 + uc * 8);
    rv1 = *(const short8*)(Vbase + (size_t)(ur + 32) * TSEQ + kt * 64 + uc * 8);
  };
  auto storeKV = [&](int c) {
    char* KB = (char*)Ks[c]; char* VB = (char*)Vs[c];
    const int chB = uc * 16;
    *(short8*)(KB + ((ur * 128 + chB) ^ ((ur & 7) << 4)))        = rk0;
    *(short8*)(KB + (((ur + 32) * 128 + chB) ^ ((ur & 7) << 4))) = rk1;
    *(short8*)(VB + ((ur * 128 + chB) ^ ((ur & 7) << 4)))        = rv0;
    *(short8*)(VB + (((ur + 32) * 128 + chB) ^ ((ur & 7) << 4))) = rv1;
  };
  loadKV(0);
  storeKV(0);
  int cur = 0;
  char* PB = (char*)Ps[w];
  for (int kt = 0; kt < 32; ++kt) {
    __syncthreads();                       // buf[cur] fully staged
    if (kt < 31) loadKV(kt + 1);           // prefetch overlaps compute below
    char* KB = (char*)Ks[cur]; char* VB = (char*)Vs[cur];
    // --- S = Q K^T (rows = q in wave's 16, cols = key 0..63)
    f32x4 s[4] = {};
    __builtin_amdgcn_s_setprio(1);
    for (int ni = 0; ni < 4; ++ni) {
      int j = ni * 16 + l15, sw = (j & 7) << 4;
      short8 kf0 = *(short8*)(KB + ((j * 128 + l4 * 16) ^ sw));
      short8 kf1 = *(short8*)(KB + ((j * 128 + 64 + l4 * 16) ^ sw));
      s[ni] = MFMA(qf[0], kf0, s[ni]);
      s[ni] = MFMA(qf[1], kf1, s[ni]);
    }
    __builtin_amdgcn_s_setprio(0);
    // --- softmax-lite: p = exp(s/8), per-lane partial row-sums only
    for (int ni = 0; ni < 4; ++ni)
      for (int r = 0; r < 4; ++r) {
        float p = __expf(s[ni][r] * 0.125f);
        lsum[r] += p;
        int row = l4 * 4 + r;
        *(unsigned short*)(PB + ((row * 128 + (ni * 16 + l15) * 2) ^
                                 ((row & 7) << 4))) = f2bf(p);
      }
    short8 pf0, pf1;
    {
      int sw = (l15 & 7) << 4;
      pf0 = *(short8*)(PB + ((l15 * 128 + l4 * 16) ^ sw));
      pf1 = *(short8*)(PB + ((l15 * 128 + 64 + l4 * 16) ^ sw));
    }
    // --- O += P V
    __builtin_amdgcn_s_setprio(1);
    for (int ni = 0; ni < 4; ++ni) {
      int dd = ni * 16 + l15, sw = (dd & 7) << 4;
      short8 vf0 = *(short8*)(VB + ((dd * 128 + l4 * 16) ^ sw));
      short8 vf1 = *(short8*)(VB + ((dd * 128 + 64 + l4 * 16) ^ sw));
      O[ni] = MFMA(pf0, vf0, O[ni]);
      O[ni] = MFMA(pf1, vf1, O[ni]);
    }
    __builtin_amdgcn_s_setprio(0);
    if (kt < 31) storeKV(cur ^ 1);         // write other buffer, no race
    cur ^= 1;
  }
  for (int r = 0; r < 4; ++r) {
    float t = lsum[r];
    t += __shfl_xor(t, 1); t += __shfl_xor(t, 2);
    t += __shfl_xor(t, 4); t += __shfl_xor(t, 8);
    float inv = 1.0f / t;
    int trow = qt * 64 + w * 16 + l4 * 4 + r;
    for (int ni = 0; ni < 4; ++ni)
      Og[(size_t)(b * TSEQ + trow) * EMB + h * 64 + ni * 16 + l15] =
          f2bf(O[ni][r] * inv);
  }
}

// ---------------------------------------------------------------- launch
extern "C" void kernel_launch(void* const* d_in, const int* in_sizes, int n_in,
                              void* d_out, int out_size, void* d_ws, size_t ws_size,
                              hipStream_t stream) {
  const float* x  = (const float*)d_in[0];
  const float* Wd = (const float*)d_in[1];
  const float* tk = (const float*)d_in[2];
  const float* tq = (const float*)d_in[3];
  const float* tv = (const float*)d_in[4];
  const float* Wu = (const float*)d_in[5];
  const float* bu = (const float*)d_in[6];
  float* out = (float*)d_out;

  char* ws = (char*)d_ws;
  size_t off = 0;
  auto alloc = [&](size_t bytes) {
    void* p = ws + off;
    off += (bytes + 255) & ~(size_t)255;
    return p;
  };
  unsigned short* XB  = (unsigned short*)alloc((size_t)BT * EMB * 2);
  unsigned short* WDT = (unsigned short*)alloc((size_t)EMB * EMB * 2);
  unsigned short* WUT = (unsigned short*)alloc((size_t)EMB * EMB * 2);
  unsigned short* PKb = (unsigned short*)alloc((size_t)HEADS * SDIM * SDIM * 2);
  unsigned short* PQb = (unsigned short*)alloc((size_t)HEADS * SDIM * SDIM * 2);
  unsigned short* PVb = (unsigned short*)alloc((size_t)HEADS * SDIM * SDIM * 2);
  unsigned short* XD  = (unsigned short*)alloc((size_t)BT * EMB * 2);
  unsigned short* Qg  = (unsigned short*)alloc((size_t)NBH * TSEQ * SDIM * 2);
  unsigned short* Kg  = (unsigned short*)alloc((size_t)NBH * TSEQ * SDIM * 2);
  unsigned short* Vtr = (unsigned short*)alloc((size_t)NBH * SDIM * TSEQ * 2);
  unsigned short* Og  = (unsigned short*)alloc((size_t)BT * EMB * 2);

  const int NX4 = BT * EMB / 4, NP4 = HEADS * SDIM * SDIM / 4;
  int nconv = (NX4 + 3 * NP4 + 255) / 256;
  convert_kernel<<<nconv, 256, 0, stream>>>(x, tk, tq, tv, XB, PKb, PQb, PVb);
  transpose_w_kernel<<<dim3(32, 32, 2), 256, 0, stream>>>(Wd, Wu, WDT, WUT);
  gemm_bt_kernel<0><<<dim3(8, 64), 256, 0, stream>>>(XB, WDT, XD, nullptr, nullptr);
  proj_qkv_kernel<<<dim3(32, 32), 256, 0, stream>>>(XD, PKb, PQb, PVb, Qg, Kg, Vtr);
  attn_kernel<<<dim3(32, 32), 256, 0, stream>>>(Qg, Kg, Vtr, Og);
  gemm_bt_kernel<1><<<dim3(8, 64), 256, 0, stream>>>(Og, WUT, nullptr, out, bu);
}